// Round 6
// baseline (657.979 us; speedup 1.0000x reference)
//
#include <hip/hip_runtime.h>
#include <stdint.h>

typedef __attribute__((ext_vector_type(8))) short short8;
typedef __attribute__((ext_vector_type(4))) float f32x4;
typedef __attribute__((ext_vector_type(4))) int i32x4;

#define DMODEL 768
#define HID    2048
#define MROWS  4096   // 2*2048 tokens

// B-spline constants: h = (4-(-4))/(16-3) = 8/13
#define KINVH  (13.0f/8.0f)
#define KNOT0  (-4.0f - 3.0f*(8.0f/13.0f))

__device__ __forceinline__ unsigned short f2bf(float f) {
  unsigned int u = __float_as_uint(f);
  unsigned int r = (u + 0x7FFFu + ((u >> 16) & 1u)) >> 16;
  return (unsigned short)r;
}

// ---- weight f32 -> bf16 bits (4 elems/thread) ----
__global__ void __launch_bounds__(256) conv_bf16(const float* __restrict__ src,
                                                 unsigned short* __restrict__ dst,
                                                 int n4) {
  int i = blockIdx.x * 256 + threadIdx.x;
  if (i >= n4) return;
  float4 v = ((const float4*)src)[i];
  ushort4 o;
  o.x = f2bf(v.x); o.y = f2bf(v.y); o.z = f2bf(v.z); o.w = f2bf(v.w);
  ((ushort4*)dst)[i] = o;
}

// ---- split-K=2 reduce, in place: p[i] = p[i] + p[i+n4] ----
__global__ void __launch_bounds__(256) reduce2(float4* __restrict__ p, int n4) {
  int i = blockIdx.x * 256 + threadIdx.x;
  if (i >= n4) return;
  float4 a = p[i], b = p[i + n4];
  float4 r;
  r.x = a.x + b.x; r.y = a.y + b.y; r.z = a.z + b.z; r.w = a.w + b.w;
  p[i] = r;
}

// ---- split-K=4 reduce: out[i] = sum over 4 planes ----
__global__ void __launch_bounds__(256) reduce4(const float4* __restrict__ p,
                                               float4* __restrict__ out, int n4) {
  int i = blockIdx.x * 256 + threadIdx.x;
  if (i >= n4) return;
  float4 a = p[i], b = p[i + n4], c = p[i + 2 * n4], d = p[i + 3 * n4];
  float4 r;
  r.x = a.x + b.x + c.x + d.x;
  r.y = a.y + b.y + c.y + d.y;
  r.z = a.z + b.z + c.z + d.z;
  r.w = a.w + b.w + c.w + d.w;
  out[i] = r;
}

// ---- fused basis + GEMM (round-2 proven structure: 2-barrier, single buffer) ----
// C[n,o] = sum_{d,k} basis(X[n,d])_k * Wb[o, d*16+k]
// X: (MROWS, DIN) f32.  Wb: (DOUT, DIN*16) bf16 bits row-major.
// One f32 plane per blockIdx.z (split-K partials), plain stores.
// Tile: BM x 128, BK=64 (4 x-columns per step). 256 threads = 4 waves in 2x2.
// BM=64: VGPR ~50 + 32 AGPR, LDS 24KB -> ~5 blocks/CU resident (the occupancy
// that made r2/r5-GEMM2 hit ~43% MFMA util).
template<int DIN, int DOUT, int BM, int SPLITK>
__global__ void __launch_bounds__(256, 2)
kan_gemm(const float* __restrict__ X, const unsigned short* __restrict__ Wb,
         float* __restrict__ Out) {
  constexpr int NK  = (DIN * 16) / 64;
  constexpr int NKS = NK / SPLITK;
  constexpr int FM  = BM / 32;          // 16x16 frags per wave in M
  constexpr int NIT = (BM * 4) / 256;   // basis iterations per step
  __shared__ __align__(16) char smA[BM * 128];    // BM rows x 64 bf16 (swizzled)
  __shared__ __align__(16) char smB[128 * 128];   // 128 rows x 64 bf16 (swizzled via source)

  const int tid  = threadIdx.x;
  const int lane = tid & 63;
  const int wid  = tid >> 6;
  const int wr   = wid >> 1;
  const int wc   = wid & 1;
  const int brow = blockIdx.x * BM;
  const int bcol = blockIdx.y * 128;
  const int kt0  = blockIdx.z * NKS;
  const int kt1  = kt0 + NKS;

  f32x4 acc[FM][4];
#pragma unroll
  for (int m = 0; m < FM; ++m)
#pragma unroll
    for (int n = 0; n < 4; ++n) acc[m][n] = (f32x4){0.f, 0.f, 0.f, 0.f};

  // fragment LDS addressing (constant per lane; kk added in-loop)
  int a_base[FM], a_sw[FM], b_base[4], b_sw[4];
#pragma unroll
  for (int m = 0; m < FM; ++m) {
    int row   = wr * (BM / 2) + m * 16 + (lane & 15);
    a_base[m] = row * 128 + ((lane >> 4) * 16);
    a_sw[m]   = (row & 7) << 4;
  }
#pragma unroll
  for (int n = 0; n < 4; ++n) {
    int row   = wc * 64 + n * 16 + (lane & 15);
    b_base[n] = row * 128 + ((lane >> 4) * 16);
    b_sw[n]   = (row & 7) << 4;
  }

  // basis-thread coordinates (constant per thread)
  int br_[NIT], bd_[NIT];
#pragma unroll
  for (int it = 0; it < NIT; ++it) {
    int idx = tid + it * 256;
    br_[it] = idx >> 2;
    bd_[it] = idx & 3;
  }

  // prologue: prefetch X for kt0
  float xcur[NIT], xnext[NIT];
#pragma unroll
  for (int it = 0; it < NIT; ++it)
    xcur[it] = X[(size_t)(brow + br_[it]) * DIN + kt0 * 4 + bd_[it]];

  for (int kt = kt0; kt < kt1; ++kt) {
    __syncthreads();   // previous compute done before overwriting LDS

    // ---- stage B: 16KB via global_load_lds width-16, pre-swizzled source.
    // LDS physical 16B-unit u at row r holds global chunk u ^ (r&7);
    // read side XORs (row&7)<<4.
#pragma unroll
    for (int i = 0; i < 4; ++i) {
      const int c   = wid * 4 + i;              // wave-uniform chunk (8 rows)
      const int row = c * 8 + (lane >> 3);
      const int gch = (lane & 7) ^ (lane >> 3);
      const unsigned short* src =
          Wb + (size_t)(bcol + row) * (DIN * 16) + kt * 64 + gch * 8;
      __builtin_amdgcn_global_load_lds(
          (const __attribute__((address_space(1))) unsigned int*)src,
          (__attribute__((address_space(3))) unsigned int*)(smB + c * 1024),
          16, 0, 0);
    }

    // ---- stage A: basis from prefetched xcur, scatter to swizzled LDS
#pragma unroll
    for (int it = 0; it < NIT; ++it) {
      int   r  = br_[it], dc = bd_[it];
      float xv = xcur[it];
      float u  = (xv - KNOT0) * KINVH;
      float uf = floorf(u);
      int   jj = (int)uf;
      float t  = u - uf;
      float t2 = t * t, t3 = t2 * t;
      float p0 = (1.0f / 6.0f) * (1.0f - 3.0f * t + 3.0f * t2 - t3);
      float p1 = (1.0f / 6.0f) * (4.0f - 6.0f * t2 + 3.0f * t3);
      float p2 = (1.0f / 6.0f) * (1.0f + 3.0f * t + 3.0f * t2 - 3.0f * t3);
      float p3 = (1.0f / 6.0f) * t3;

      int base = r * 128 + dc * 32;
      int sw   = (r & 7) << 4;
      *(i32x4*)(smA + (base ^ sw))        = (i32x4){0, 0, 0, 0};
      *(i32x4*)(smA + ((base + 16) ^ sw)) = (i32x4){0, 0, 0, 0};
      unsigned short q0 = f2bf(p0), q1 = f2bf(p1), q2 = f2bf(p2), q3 = f2bf(p3);
      int k0 = jj - 3;
      if ((unsigned)(k0 + 0) < 16u) *(unsigned short*)(smA + ((base + (k0 + 0) * 2) ^ sw)) = q0;
      if ((unsigned)(k0 + 1) < 16u) *(unsigned short*)(smA + ((base + (k0 + 1) * 2) ^ sw)) = q1;
      if ((unsigned)(k0 + 2) < 16u) *(unsigned short*)(smA + ((base + (k0 + 2) * 2) ^ sw)) = q2;
      if ((unsigned)(k0 + 3) < 16u) *(unsigned short*)(smA + ((base + (k0 + 3) * 2) ^ sw)) = q3;
    }

    // ---- prefetch X for next step (latency drains under the same barrier as B)
    {
      int ktn = (kt + 1 < kt1) ? kt + 1 : kt;
#pragma unroll
      for (int it = 0; it < NIT; ++it)
        xnext[it] = X[(size_t)(brow + br_[it]) * DIN + ktn * 4 + bd_[it]];
    }

    __syncthreads();   // drains LDS writes AND vmem (B tile + X prefetch)

    // ---- compute: 2 k-chunks of 32
#pragma unroll
    for (int kk = 0; kk < 2; ++kk) {
      short8 av[FM], bv[4];
#pragma unroll
      for (int m = 0; m < FM; ++m)
        av[m] = *(const short8*)(smA + ((a_base[m] + kk * 64) ^ a_sw[m]));
#pragma unroll
      for (int n = 0; n < 4; ++n)
        bv[n] = *(const short8*)(smB + ((b_base[n] + kk * 64) ^ b_sw[n]));
#pragma unroll
      for (int m = 0; m < FM; ++m)
#pragma unroll
        for (int n = 0; n < 4; ++n)
          acc[m][n] = __builtin_amdgcn_mfma_f32_16x16x32_bf16(av[m], bv[n], acc[m][n], 0, 0, 0);
    }

#pragma unroll
    for (int it = 0; it < NIT; ++it) xcur[it] = xnext[it];
  }

  // ---- epilogue: C/D layout col=lane&15, row=(lane>>4)*4+q
  float* outp = Out + (size_t)blockIdx.z * MROWS * DOUT;
#pragma unroll
  for (int m = 0; m < FM; ++m)
#pragma unroll
    for (int n = 0; n < 4; ++n)
#pragma unroll
      for (int q = 0; q < 4; ++q) {
        int grow = brow + wr * (BM / 2) + m * 16 + (lane >> 4) * 4 + q;
        int gcol = bcol + wc * 64 + n * 16 + (lane & 15);
        outp[(size_t)grow * DOUT + gcol] = acc[m][n][q];
      }
}

extern "C" void kernel_launch(void* const* d_in, const int* in_sizes, int n_in,
                              void* d_out, int out_size, void* d_ws, size_t ws_size,
                              hipStream_t stream) {
  const float* x  = (const float*)d_in[0];   // (2,2048,768) f32 -> (4096,768)
  const float* w1 = (const float*)d_in[1];   // (2048,768,16) f32
  const float* w2 = (const float*)d_in[2];   // (768,2048,16) f32
  float* out = (float*)d_out;                // (4096,768) f32

  // ws timeline (128 MiB):
  //   [0, 50.33M)      : w1b (phase 1), then w2b (phase 2, after GEMM1)
  //   [50.33M, 83.89M) : GEMM1 partial plane 0 -> becomes h (f32) after reduce2
  //   [83.89M,117.44M) : GEMM1 partial plane 1 (dead after reduce2)
  //   [83.89M,134.22M) : GEMM2 partial planes 0..3 (overwrites plane 1)
  char* ws = (char*)d_ws;
  unsigned short* wgb   = (unsigned short*)ws;                  // 50,331,648 B
  float*          part1 = (float*)(ws + 50331648);              // 2 x 33,554,432 B
  float*          hbf   = part1;                                // alias: plane 0
  float*          part2 = (float*)(ws + 83886080);              // 4 x 12,582,912 B (end = 128MiB)

  const int n4 = (HID * DMODEL * 16) / 4;    // 6,291,456 float4 groups per weight

  // phase 1: layer 1
  conv_bf16<<<n4 / 256, 256, 0, stream>>>(w1, wgb, n4);
  // split-K=2, plain partial planes: 2048 blocks (~8/CU available, ~5 resident)
  kan_gemm<DMODEL, HID, 64, 2>
      <<<dim3(MROWS / 64, HID / 128, 2), 256, 0, stream>>>(x, wgb, part1);
  const int hn4 = (MROWS * HID) / 4;         // 2,097,152
  reduce2<<<hn4 / 256, 256, 0, stream>>>((float4*)part1, hn4);   // h = plane0

  // phase 2: layer 2 (convert w2 now that w1b is dead)
  conv_bf16<<<n4 / 256, 256, 0, stream>>>(w2, wgb, n4);
  kan_gemm<HID, DMODEL, 64, 4>
      <<<dim3(MROWS / 64, DMODEL / 128, 4), 256, 0, stream>>>(hbf, wgb, part2);
  const int rn4 = (MROWS * DMODEL) / 4;      // 786,432
  reduce4<<<rn4 / 256, 256, 0, stream>>>((const float4*)part2, (float4*)out, rn4);
}

// Round 7
// 591.687 us; speedup vs baseline: 1.1120x; 1.1120x over previous
//
#include <hip/hip_runtime.h>
#include <stdint.h>

typedef __attribute__((ext_vector_type(8))) short short8;
typedef __attribute__((ext_vector_type(4))) float f32x4;
typedef __attribute__((ext_vector_type(4))) int i32x4;

#define DMODEL 768
#define HID    2048
#define MROWS  4096   // 2*2048 tokens

// B-spline constants: h = (4-(-4))/(16-3) = 8/13
#define KINVH  (13.0f/8.0f)
#define KNOT0  (-4.0f - 3.0f*(8.0f/13.0f))

__device__ __forceinline__ unsigned short f2bf(float f) {
  unsigned int u = __float_as_uint(f);
  unsigned int r = (u + 0x7FFFu + ((u >> 16) & 1u)) >> 16;
  return (unsigned short)r;
}

// ---- weight f32 -> bf16 bits (4 elems/thread) ----
__global__ void __launch_bounds__(256) conv_bf16(const float* __restrict__ src,
                                                 unsigned short* __restrict__ dst,
                                                 int n4) {
  int i = blockIdx.x * 256 + threadIdx.x;
  if (i >= n4) return;
  float4 v = ((const float4*)src)[i];
  ushort4 o;
  o.x = f2bf(v.x); o.y = f2bf(v.y); o.z = f2bf(v.z); o.w = f2bf(v.w);
  ((ushort4*)dst)[i] = o;
}

// ---- split-K=2 reduce, in place: p[i] = p[i] + p[i+n4] ----
__global__ void __launch_bounds__(256) reduce2(float4* __restrict__ p, int n4) {
  int i = blockIdx.x * 256 + threadIdx.x;
  if (i >= n4) return;
  float4 a = p[i], b = p[i + n4];
  float4 r;
  r.x = a.x + b.x; r.y = a.y + b.y; r.z = a.z + b.z; r.w = a.w + b.w;
  p[i] = r;
}

// ---- split-K=4 reduce: out[i] = sum over 4 planes ----
__global__ void __launch_bounds__(256) reduce4(const float4* __restrict__ p,
                                               float4* __restrict__ out, int n4) {
  int i = blockIdx.x * 256 + threadIdx.x;
  if (i >= n4) return;
  float4 a = p[i], b = p[i + n4], c = p[i + 2 * n4], d = p[i + 3 * n4];
  float4 r;
  r.x = a.x + b.x + c.x + d.x;
  r.y = a.y + b.y + c.y + d.y;
  r.z = a.z + b.z + c.z + d.z;
  r.w = a.w + b.w + c.w + d.w;
  out[i] = r;
}

// ---- fused basis + GEMM ----
// C[n,o] = sum_{d,k} basis(X[n,d])_k * Wb[o, d*16+k]
// Tile: BM=64 x BN=256, BK=64 (4 x-columns per step). 4 waves in 1x4:
// each wave owns the full 64 rows x a 64-col band -> wave tile 64x64
// (FM=4, FN=4, 16 MFMA per kk-half, 0.5 ds_read_b128 per MFMA —
// the LDS-volume fix; r6's 32x64 wave tile was 0.75/MFMA and LDS-pipe-bound).
// LDS 40KB (8KB A + 32KB B) -> 4 blocks/CU cap.
template<int DIN, int DOUT, int SPLITK>
__global__ void __launch_bounds__(256, 2)
kan_gemm(const float* __restrict__ X, const unsigned short* __restrict__ Wb,
         float* __restrict__ Out) {
  constexpr int BM  = 64;
  constexpr int BN  = 256;
  constexpr int NK  = (DIN * 16) / 64;
  constexpr int NKS = NK / SPLITK;
  constexpr int FM  = 4;
  constexpr int FN  = 4;
  __shared__ __align__(16) char smA[BM * 128];   // 64 rows x 64 bf16 (swizzled) = 8KB
  __shared__ __align__(16) char smB[BN * 128];   // 256 rows x 64 bf16 (swizzled via source) = 32KB

  const int tid  = threadIdx.x;
  const int lane = tid & 63;
  const int wid  = tid >> 6;
  const int brow = blockIdx.x * BM;
  const int bcol = blockIdx.y * BN;
  const int kt0  = blockIdx.z * NKS;
  const int kt1  = kt0 + NKS;

  f32x4 acc[FM][FN];
#pragma unroll
  for (int m = 0; m < FM; ++m)
#pragma unroll
    for (int n = 0; n < FN; ++n) acc[m][n] = (f32x4){0.f, 0.f, 0.f, 0.f};

  // fragment LDS addressing (constant per lane; kk added in-loop)
  int a_base[FM], a_sw[FM], b_base[FN], b_sw[FN];
#pragma unroll
  for (int m = 0; m < FM; ++m) {
    int row   = m * 16 + (lane & 15);
    a_base[m] = row * 128 + ((lane >> 4) * 16);
    a_sw[m]   = (row & 7) << 4;
  }
#pragma unroll
  for (int n = 0; n < FN; ++n) {
    int row   = wid * 64 + n * 16 + (lane & 15);
    b_base[n] = row * 128 + ((lane >> 4) * 16);
    b_sw[n]   = (row & 7) << 4;
  }

  // basis-thread coordinates: 256 threads cover 64 rows x 4 d-cols
  const int br_ = tid >> 2;
  const int bd_ = tid & 3;

  // prologue: prefetch X for kt0
  float xcur, xnext;
  xcur = X[(size_t)(brow + br_) * DIN + kt0 * 4 + bd_];

  for (int kt = kt0; kt < kt1; ++kt) {
    __syncthreads();   // previous compute done before overwriting LDS

    // ---- stage B: 32KB via global_load_lds width-16, pre-swizzled source.
    // LDS physical 16B-unit u at row r holds global chunk u ^ (r&7);
    // read side XORs (row&7)<<4.
#pragma unroll
    for (int i = 0; i < 8; ++i) {
      const int c   = wid * 8 + i;              // wave-uniform chunk (8 rows = 1KB)
      const int row = c * 8 + (lane >> 3);
      const int gch = (lane & 7) ^ (lane >> 3);
      const unsigned short* src =
          Wb + (size_t)(bcol + row) * (DIN * 16) + kt * 64 + gch * 8;
      __builtin_amdgcn_global_load_lds(
          (const __attribute__((address_space(1))) unsigned int*)src,
          (__attribute__((address_space(3))) unsigned int*)(smB + c * 1024),
          16, 0, 0);
    }

    // ---- stage A: basis from prefetched xcur, scatter to swizzled LDS
    {
      int   r  = br_, dc = bd_;
      float u  = (xcur - KNOT0) * KINVH;
      float uf = floorf(u);
      int   jj = (int)uf;
      float t  = u - uf;
      float t2 = t * t, t3 = t2 * t;
      float p0 = (1.0f / 6.0f) * (1.0f - 3.0f * t + 3.0f * t2 - t3);
      float p1 = (1.0f / 6.0f) * (4.0f - 6.0f * t2 + 3.0f * t3);
      float p2 = (1.0f / 6.0f) * (1.0f + 3.0f * t + 3.0f * t2 - 3.0f * t3);
      float p3 = (1.0f / 6.0f) * t3;

      int base = r * 128 + dc * 32;
      int sw   = (r & 7) << 4;
      *(i32x4*)(smA + (base ^ sw))        = (i32x4){0, 0, 0, 0};
      *(i32x4*)(smA + ((base + 16) ^ sw)) = (i32x4){0, 0, 0, 0};
      unsigned short q0 = f2bf(p0), q1 = f2bf(p1), q2 = f2bf(p2), q3 = f2bf(p3);
      int k0 = jj - 3;
      if ((unsigned)(k0 + 0) < 16u) *(unsigned short*)(smA + ((base + (k0 + 0) * 2) ^ sw)) = q0;
      if ((unsigned)(k0 + 1) < 16u) *(unsigned short*)(smA + ((base + (k0 + 1) * 2) ^ sw)) = q1;
      if ((unsigned)(k0 + 2) < 16u) *(unsigned short*)(smA + ((base + (k0 + 2) * 2) ^ sw)) = q2;
      if ((unsigned)(k0 + 3) < 16u) *(unsigned short*)(smA + ((base + (k0 + 3) * 2) ^ sw)) = q3;
    }

    // ---- prefetch X for next step (latency drains under the same barrier as B)
    {
      int ktn = (kt + 1 < kt1) ? kt + 1 : kt;
      xnext = X[(size_t)(brow + br_) * DIN + ktn * 4 + bd_];
    }

    __syncthreads();   // drains LDS writes AND vmem (B tile + X prefetch)

    // ---- compute: 2 k-chunks of 32
#pragma unroll
    for (int kk = 0; kk < 2; ++kk) {
      short8 av[FM], bv[FN];
#pragma unroll
      for (int m = 0; m < FM; ++m)
        av[m] = *(const short8*)(smA + ((a_base[m] + kk * 64) ^ a_sw[m]));
#pragma unroll
      for (int n = 0; n < FN; ++n)
        bv[n] = *(const short8*)(smB + ((b_base[n] + kk * 64) ^ b_sw[n]));
#pragma unroll
      for (int m = 0; m < FM; ++m)
#pragma unroll
        for (int n = 0; n < FN; ++n)
          acc[m][n] = __builtin_amdgcn_mfma_f32_16x16x32_bf16(av[m], bv[n], acc[m][n], 0, 0, 0);
    }

    xcur = xnext;
  }

  // ---- epilogue: C/D layout col=lane&15, row=(lane>>4)*4+q
  float* outp = Out + (size_t)blockIdx.z * MROWS * DOUT;
#pragma unroll
  for (int m = 0; m < FM; ++m)
#pragma unroll
    for (int n = 0; n < FN; ++n)
#pragma unroll
      for (int q = 0; q < 4; ++q) {
        int grow = brow + m * 16 + (lane >> 4) * 4 + q;
        int gcol = bcol + wid * 64 + n * 16 + (lane & 15);
        outp[(size_t)grow * DOUT + gcol] = acc[m][n][q];
      }
}

extern "C" void kernel_launch(void* const* d_in, const int* in_sizes, int n_in,
                              void* d_out, int out_size, void* d_ws, size_t ws_size,
                              hipStream_t stream) {
  const float* x  = (const float*)d_in[0];   // (2,2048,768) f32 -> (4096,768)
  const float* w1 = (const float*)d_in[1];   // (2048,768,16) f32
  const float* w2 = (const float*)d_in[2];   // (768,2048,16) f32
  float* out = (float*)d_out;                // (4096,768) f32

  // ws timeline (128 MiB):
  //   [0, 48M)   : w1b (phase 1), then w2b (phase 2, after GEMM1)
  //   [48M, 80M) : GEMM1 partial plane 0 -> becomes h (f32) after reduce2
  //   [80M, 112M): GEMM1 partial plane 1 (dead after reduce2)
  //   [80M, 128M): GEMM2 partial planes 0..3 (overwrites plane 1)
  char* ws = (char*)d_ws;
  unsigned short* wgb   = (unsigned short*)ws;                  // 50,331,648 B
  float*          part1 = (float*)(ws + 50331648);              // 2 x 33,554,432 B
  float*          hbf   = part1;                                // alias: plane 0
  float*          part2 = (float*)(ws + 83886080);              // 4 x 12,582,912 B (end = 128MiB)

  const int n4 = (HID * DMODEL * 16) / 4;    // 6,291,456 float4 groups per weight

  // phase 1: layer 1
  conv_bf16<<<n4 / 256, 256, 0, stream>>>(w1, wgb, n4);
  // split-K=2, plain partial planes: 1024 blocks = 4/CU
  kan_gemm<DMODEL, HID, 2>
      <<<dim3(MROWS / 64, HID / 256, 2), 256, 0, stream>>>(x, wgb, part1);
  const int hn4 = (MROWS * HID) / 4;         // 2,097,152
  reduce2<<<hn4 / 256, 256, 0, stream>>>((float4*)part1, hn4);   // h = plane0

  // phase 2: layer 2 (convert w2 now that w1b is dead)
  conv_bf16<<<n4 / 256, 256, 0, stream>>>(w2, wgb, n4);
  kan_gemm<HID, DMODEL, 4>
      <<<dim3(MROWS / 64, DMODEL / 256, 4), 256, 0, stream>>>(hbf, wgb, part2);
  const int rn4 = (MROWS * DMODEL) / 4;      // 786,432
  reduce4<<<rn4 / 256, 256, 0, stream>>>((const float4*)part2, (float4*)out, rn4);
}